// Round 1
// baseline (1059.373 us; speedup 1.0000x reference)
//
#include <hip/hip_runtime.h>
#include <hip/hip_bf16.h>

// Problem constants
#define BATCH 8
#define SEQ   2048
#define CDIM  1024
#define HDIM  64
#define NROWS (BATCH*SEQ)   // 16384

// ---------------------------------------------------------------------------
// Kernel 1: fused QKV projection.
// grid = (NROWS, 3); block = 256 threads (64 dims x 4 c-chunks).
// which = blockIdx.y: 0->q, 1->k, 2->v.  W is [C][D] row-major.
// ---------------------------------------------------------------------------
__global__ __launch_bounds__(256) void qkv_proj(
    const float* __restrict__ x,
    const float* __restrict__ Wq,
    const float* __restrict__ Wk,
    const float* __restrict__ Wv,
    float* __restrict__ qkv)   // [3][NROWS][64]
{
    const int r     = blockIdx.x;
    const int which = blockIdx.y;
    const float* W = (which == 0) ? Wq : (which == 1) ? Wk : Wv;

    __shared__ float xs[CDIM];
    __shared__ float ps[4][HDIM];

    const int t = threadIdx.x;          // 0..255
    // stage x row into LDS (256 threads x float4 = 1024 floats)
    const float4* xr = reinterpret_cast<const float4*>(x + (size_t)r * CDIM);
    reinterpret_cast<float4*>(xs)[t] = xr[t];
    __syncthreads();

    const int d     = t & 63;
    const int chunk = t >> 6;           // 0..3
    const float* Wp = W + d;

    float s = 0.f;
    const int c0 = chunk * 256;
    #pragma unroll 4
    for (int c = c0; c < c0 + 256; c += 4) {
        float4 xv = *reinterpret_cast<const float4*>(&xs[c]);
        s += xv.x * Wp[(c + 0) * HDIM];
        s += xv.y * Wp[(c + 1) * HDIM];
        s += xv.z * Wp[(c + 2) * HDIM];
        s += xv.w * Wp[(c + 3) * HDIM];
    }
    ps[chunk][d] = s;
    __syncthreads();

    if (t < HDIM) {
        float tot = ps[0][t] + ps[1][t] + ps[2][t] + ps[3][t];
        qkv[(size_t)which * ((size_t)NROWS * HDIM) + (size_t)r * HDIM + t] = tot;
    }
}

// ---------------------------------------------------------------------------
// Kernel 2: causal flash attention (scalar, fp32).
// block = 256 threads = 4 waves; wave w handles query row blockIdx.x*4 + w.
// Per 64-key tile:
//   phase A: lane l scores key j0+l  (k row = 256B contiguous per lane)
//   wave-uniform online softmax (shfl_xor butterflies)
//   phase B: lane d accumulates output dim d (coalesced v reads, p via shfl)
// ---------------------------------------------------------------------------
__global__ __launch_bounds__(256) void attn_fwd(
    const float* __restrict__ q,
    const float* __restrict__ k,
    const float* __restrict__ v,
    float* __restrict__ out)
{
    const int w    = threadIdx.x >> 6;
    const int lane = threadIdx.x & 63;
    const int row  = blockIdx.x * 4 + w;      // 0..NROWS-1
    const int b    = row >> 11;               // / SEQ
    const int i    = row & (SEQ - 1);

    __shared__ float qs[4][HDIM];
    qs[w][lane] = q[(size_t)row * HDIM + lane];
    __syncthreads();

    const float* kb = k + (size_t)b * SEQ * HDIM;
    const float* vb = v + (size_t)b * SEQ * HDIM;
    const float4* q4 = reinterpret_cast<const float4*>(qs[w]);

    float m = -1e30f, l = 0.f, acc = 0.f;
    const float scale = 0.125f;               // 1/sqrt(64)

    const int ntiles = (i >> 6) + 1;
    for (int tb = 0; tb < ntiles; ++tb) {
        const int j = tb * 64 + lane;
        // ---- phase A: score for key j ----
        const float4* kr = reinterpret_cast<const float4*>(kb + (size_t)j * HDIM);
        float s = 0.f;
        #pragma unroll
        for (int c = 0; c < 16; ++c) {
            float4 kk = kr[c];
            float4 qq = q4[c];
            s += qq.x * kk.x + qq.y * kk.y + qq.z * kk.z + qq.w * kk.w;
        }
        s *= scale;
        if (j > i) s = -1e30f;                // causal mask

        // wave-wide max of tile scores
        float tmax = s;
        #pragma unroll
        for (int off = 32; off >= 1; off >>= 1)
            tmax = fmaxf(tmax, __shfl_xor(tmax, off, 64));
        const float mnew = fmaxf(m, tmax);
        float p = __expf(s - mnew);
        if (j > i) p = 0.f;
        const float corr = __expf(m - mnew);

        // wave-wide sum of p
        float psum = p;
        #pragma unroll
        for (int off = 32; off >= 1; off >>= 1)
            psum += __shfl_xor(psum, off, 64);

        l = l * corr + psum;
        m = mnew;
        acc *= corr;

        // ---- phase B: lane `lane` accumulates output dim `lane` ----
        const float* vt = vb + (size_t)tb * 64 * HDIM + lane;
        #pragma unroll 8
        for (int jj = 0; jj < 64; ++jj) {
            const float pj = __shfl(p, jj, 64);
            acc += pj * vt[jj * HDIM];
        }
    }

    out[(size_t)row * HDIM + lane] = acc / l;
}

extern "C" void kernel_launch(void* const* d_in, const int* in_sizes, int n_in,
                              void* d_out, int out_size, void* d_ws, size_t ws_size,
                              hipStream_t stream) {
    const float* x  = (const float*)d_in[0];
    const float* Wq = (const float*)d_in[1];
    const float* Wk = (const float*)d_in[2];
    const float* Wv = (const float*)d_in[3];
    float* out = (float*)d_out;

    float* qkv = (float*)d_ws;                       // 3 * 16384 * 64 floats = 12 MB
    float* qb = qkv;
    float* kb = qkv + (size_t)NROWS * HDIM;
    float* vb = qkv + 2 * (size_t)NROWS * HDIM;

    dim3 g1(NROWS, 3);
    qkv_proj<<<g1, 256, 0, stream>>>(x, Wq, Wk, Wv, qkv);

    attn_fwd<<<NROWS / 4, 256, 0, stream>>>(qb, kb, vb, out);
}

// Round 3
// 173.632 us; speedup vs baseline: 6.1013x; 6.1013x over previous
//
#include <hip/hip_runtime.h>
#include <hip/hip_bf16.h>

#define BATCH 8
#define SEQ   2048
#define CDIM  1024
#define HDIM  64
#define NROWS (BATCH*SEQ)   // 16384

typedef __attribute__((ext_vector_type(8))) short bf16x8;
typedef __attribute__((ext_vector_type(4))) float f32x4;

// 0.125 (1/sqrt(64)) * log2(e) — folded into Wq so QK^T emerges in exp2 units
#define QSCALE 0.18033688011112042f

__device__ inline ushort f2bf(float f) {
    union { float f; uint u; } x; x.f = f;
    uint r = (x.u + 0x7fffu + ((x.u >> 16) & 1u)) >> 16;
    return (ushort)r;
}

// ---------------------------------------------------------------------------
// Kernel 0: pack W^T into bf16  wp[192][1024];  n<64: Wq*QSCALE, <128: Wk, else Wv
// ---------------------------------------------------------------------------
__global__ __launch_bounds__(256) void wpack_kernel(
    const float* __restrict__ Wq, const float* __restrict__ Wk,
    const float* __restrict__ Wv, ushort* __restrict__ wp)
{
    const int n = blockIdx.x;            // 0..191
    const int which = n >> 6, nl = n & 63;
    const float* W = (which == 0) ? Wq : (which == 1) ? Wk : Wv;
    const float sc = (which == 0) ? QSCALE : 1.0f;
    for (int c = threadIdx.x; c < CDIM; c += 256)
        wp[(size_t)n * CDIM + c] = f2bf(W[(size_t)c * HDIM + nl] * sc);
}

// ---------------------------------------------------------------------------
// Kernel 1: QKV GEMM, bf16 MFMA.  out: qb[r][64] (prescaled), kbuf[r][64],
// vt[b][64 d][2048 t]  (V transposed for PV fragment loads).
// grid = 256 M-tiles of 64 rows; 256 threads = 4 waves; wave owns 16 rows x 192 cols.
// ---------------------------------------------------------------------------
__global__ __launch_bounds__(256) void qkv_gemm(
    const float* __restrict__ x, const ushort* __restrict__ wp,
    ushort* __restrict__ qb, ushort* __restrict__ kbuf, ushort* __restrict__ vt)
{
    __shared__ ushort xs[64 * 64];   // [row][c] bf16, XOR-swizzled, 8KB
    __shared__ ushort ws[192 * 64];  // [n][c]  bf16, XOR-swizzled, 24KB
    const int t = threadIdx.x;
    const int w = t >> 6, lane = t & 63;
    const int m0 = blockIdx.x * 64;

    f32x4 acc[12];
    #pragma unroll
    for (int i = 0; i < 12; ++i) acc[i] = (f32x4){0.f, 0.f, 0.f, 0.f};

    for (int kk = 0; kk < CDIM; kk += 64) {
        // stage x tile [64 rows][64 c]: fp32 -> bf16
        #pragma unroll
        for (int j = 0; j < 4; ++j) {
            const int idx = t + j * 256;
            const int row = idx >> 4, c4 = idx & 15;
            float4 xv = reinterpret_cast<const float4*>(
                x + (size_t)(m0 + row) * CDIM + kk)[c4];
            ushort4 bv = make_ushort4(f2bf(xv.x), f2bf(xv.y), f2bf(xv.z), f2bf(xv.w));
            int byte = (row * 128 + c4 * 8) ^ ((row & 7) << 4);
            *reinterpret_cast<ushort4*>(reinterpret_cast<char*>(xs) + byte) = bv;
        }
        // stage W tile [192 n][64 c] from wp (already transposed/bf16)
        #pragma unroll
        for (int j = 0; j < 6; ++j) {
            const int g = t + j * 256;
            const int n = g >> 3, c16 = g & 7;
            uint4 wv = reinterpret_cast<const uint4*>(wp + (size_t)n * CDIM + kk)[c16];
            int byte = (n * 128 + c16 * 16) ^ ((n & 7) << 4);
            *reinterpret_cast<uint4*>(reinterpret_cast<char*>(ws) + byte) = wv;
        }
        __syncthreads();
        #pragma unroll
        for (int c32 = 0; c32 < 2; ++c32) {
            const int arow = w * 16 + (lane & 15);
            const int abyte = (arow * 128 + (lane >> 4) * 16 + c32 * 64) ^ ((arow & 7) << 4);
            bf16x8 a = *reinterpret_cast<const bf16x8*>(reinterpret_cast<char*>(xs) + abyte);
            #pragma unroll
            for (int nf = 0; nf < 12; ++nf) {
                const int n = nf * 16 + (lane & 15);
                const int bbyte = (n * 128 + (lane >> 4) * 16 + c32 * 64) ^ ((n & 7) << 4);
                bf16x8 b = *reinterpret_cast<const bf16x8*>(reinterpret_cast<char*>(ws) + bbyte);
                acc[nf] = __builtin_amdgcn_mfma_f32_16x16x32_bf16(a, b, acc[nf], 0, 0, 0);
            }
        }
        __syncthreads();
    }
    // epilogue: C layout col = lane&15 (n), row = (lane>>4)*4 + r
    #pragma unroll
    for (int nf = 0; nf < 12; ++nf) {
        const int n = nf * 16 + (lane & 15);
        #pragma unroll
        for (int r = 0; r < 4; ++r) {
            const int grow = m0 + w * 16 + (lane >> 4) * 4 + r;
            const ushort bv = f2bf(acc[nf][r]);
            if (n < 64) {
                qb[(size_t)grow * 64 + n] = bv;
            } else if (n < 128) {
                kbuf[(size_t)grow * 64 + (n - 64)] = bv;
            } else {
                const int b = grow >> 11, tt = grow & 2047;
                vt[(((size_t)b * 64 + (n - 128)) << 11) + tt] = bv;
            }
        }
    }
}

// ---------------------------------------------------------------------------
// Kernel 2: MFMA flash attention.  1024 one-wave blocks; block = one 16-row
// q-tile.  K/V fragments read straight from global (L2-resident, 256KB/batch).
// Adjacent blocks take complementary causal loads (qt, 127-qt) for balance.
// ---------------------------------------------------------------------------
__global__ __launch_bounds__(64) void attn_mfma(
    const ushort* __restrict__ qb, const ushort* __restrict__ kbuf,
    const ushort* __restrict__ vt, float* __restrict__ out)
{
    __shared__ ushort P[16 * 64];   // P round-trip buffer, XOR-swizzled, 2KB
    const int lane = threadIdx.x;
    const int g = blockIdx.x;
    const int pid = g >> 1, s = g & 1;
    const int qt = s ? (127 - (pid & 127)) : (pid & 127);
    const int batch = ((pid >> 7) << 1) | s;
    const int qbase = qt * 16;                  // within batch
    const int row0 = batch * SEQ + qbase;       // global q row base

    // Q A-fragments (prescaled by QSCALE at GEMM time)
    const int c0 = (lane >> 4) * 8;
    const ushort* qp = qb + (size_t)(row0 + (lane & 15)) * 64 + c0;
    bf16x8 aq0 = *reinterpret_cast<const bf16x8*>(qp);
    bf16x8 aq1 = *reinterpret_cast<const bf16x8*>(qp + 32);

    f32x4 O[4];
    #pragma unroll
    for (int i = 0; i < 4; ++i) O[i] = (f32x4){0.f, 0.f, 0.f, 0.f};
    float m[4]    = {-1e30f, -1e30f, -1e30f, -1e30f};
    float lsum[4] = {0.f, 0.f, 0.f, 0.f};

    const ushort* kB = kbuf + (size_t)batch * SEQ * 64;
    const ushort* vB = vt + (size_t)batch * 64 * SEQ;

    const int ntiles = (qbase >> 6) + 1;
    for (int kt = 0; kt < ntiles; ++kt) {
        const int j0 = kt * 64;
        // ---- QK^T: S[16 q][64 k] in exp2 units ----
        f32x4 S[4];
        #pragma unroll
        for (int kb = 0; kb < 4; ++kb) {
            const int key = j0 + kb * 16 + (lane & 15);
            const ushort* kp = kB + (size_t)key * 64 + c0;
            bf16x8 b0 = *reinterpret_cast<const bf16x8*>(kp);
            bf16x8 b1 = *reinterpret_cast<const bf16x8*>(kp + 32);
            f32x4 z = (f32x4){0.f, 0.f, 0.f, 0.f};
            z = __builtin_amdgcn_mfma_f32_16x16x32_bf16(aq0, b0, z, 0, 0, 0);
            z = __builtin_amdgcn_mfma_f32_16x16x32_bf16(aq1, b1, z, 0, 0, 0);
            S[kb] = z;
        }
        // ---- causal mask ----
        #pragma unroll
        for (int kb = 0; kb < 4; ++kb) {
            const int key = j0 + kb * 16 + (lane & 15);
            #pragma unroll
            for (int r = 0; r < 4; ++r) {
                const int qr = qbase + (lane >> 4) * 4 + r;
                if (key > qr) S[kb][r] = -1e30f;
            }
        }
        // ---- online softmax (row lives in 16 lanes of a quarter) ----
        float corr[4];
        #pragma unroll
        for (int r = 0; r < 4; ++r) {
            float tmax = fmaxf(fmaxf(S[0][r], S[1][r]), fmaxf(S[2][r], S[3][r]));
            #pragma unroll
            for (int off = 1; off <= 8; off <<= 1)
                tmax = fmaxf(tmax, __shfl_xor(tmax, off, 64));
            const float mnew = fmaxf(m[r], tmax);
            corr[r] = exp2f(m[r] - mnew);
            m[r] = mnew;
        }
        float psum[4] = {0.f, 0.f, 0.f, 0.f};
        #pragma unroll
        for (int kb = 0; kb < 4; ++kb) {
            #pragma unroll
            for (int r = 0; r < 4; ++r) {
                const float pv = exp2f(S[kb][r] - m[r]);   // masked -> 0
                S[kb][r] = pv;
                psum[r] += pv;
            }
        }
        #pragma unroll
        for (int r = 0; r < 4; ++r) {
            float ps = psum[r];
            #pragma unroll
            for (int off = 1; off <= 8; off <<= 1)
                ps += __shfl_xor(ps, off, 64);
            lsum[r] = lsum[r] * corr[r] + ps;
        }
        #pragma unroll
        for (int dt = 0; dt < 4; ++dt)
            #pragma unroll
            for (int r = 0; r < 4; ++r)
                O[dt][r] *= corr[r];
        // ---- P: C-layout -> LDS (swizzled) -> A-layout ----
        #pragma unroll
        for (int kb = 0; kb < 4; ++kb) {
            #pragma unroll
            for (int r = 0; r < 4; ++r) {
                const int prow = (lane >> 4) * 4 + r;
                const int pcol = kb * 16 + (lane & 15);
                const int byte = (prow * 128 + pcol * 2) ^ ((prow & 7) << 4);
                *reinterpret_cast<ushort*>(reinterpret_cast<char*>(P) + byte)
                    = f2bf(S[kb][r]);
            }
        }
        __syncthreads();
        const int prow = lane & 15;
        const int pb0 = (prow * 128 + (lane >> 4) * 16) ^ ((prow & 7) << 4);
        const int pb1 = (prow * 128 + (lane >> 4) * 16 + 64) ^ ((prow & 7) << 4);
        bf16x8 pa0 = *reinterpret_cast<const bf16x8*>(reinterpret_cast<char*>(P) + pb0);
        bf16x8 pa1 = *reinterpret_cast<const bf16x8*>(reinterpret_cast<char*>(P) + pb1);
        // ---- PV: O += P[16][64] * V[64][64] ----
        #pragma unroll
        for (int dt = 0; dt < 4; ++dt) {
            const int d = dt * 16 + (lane & 15);
            const ushort* vp = vB + (size_t)d * SEQ + j0 + (lane >> 4) * 8;
            bf16x8 v0 = *reinterpret_cast<const bf16x8*>(vp);
            bf16x8 v1 = *reinterpret_cast<const bf16x8*>(vp + 32);
            O[dt] = __builtin_amdgcn_mfma_f32_16x16x32_bf16(pa0, v0, O[dt], 0, 0, 0);
            O[dt] = __builtin_amdgcn_mfma_f32_16x16x32_bf16(pa1, v1, O[dt], 0, 0, 0);
        }
        __syncthreads();
    }
    // ---- epilogue ----
    #pragma unroll
    for (int dt = 0; dt < 4; ++dt) {
        #pragma unroll
        for (int r = 0; r < 4; ++r) {
            const int grow = row0 + (lane >> 4) * 4 + r;
            const int col = dt * 16 + (lane & 15);
            out[(size_t)grow * 64 + col] = O[dt][r] / lsum[r];
        }
    }
}

extern "C" void kernel_launch(void* const* d_in, const int* in_sizes, int n_in,
                              void* d_out, int out_size, void* d_ws, size_t ws_size,
                              hipStream_t stream) {
    const float* x  = (const float*)d_in[0];
    const float* Wq = (const float*)d_in[1];
    const float* Wk = (const float*)d_in[2];
    const float* Wv = (const float*)d_in[3];
    float* out = (float*)d_out;

    ushort* qb   = (ushort*)d_ws;                    // 2MB
    ushort* kbuf = qb + (size_t)NROWS * 64;          // 2MB
    ushort* vt   = kbuf + (size_t)NROWS * 64;        // 2MB (transposed V)
    ushort* wp   = vt + (size_t)NROWS * 64;          // 384KB packed W^T

    wpack_kernel<<<192, 256, 0, stream>>>(Wq, Wk, Wv, wp);
    qkv_gemm<<<NROWS / 64, 256, 0, stream>>>(x, wp, qb, kbuf, vt);
    attn_mfma<<<1024, 64, 0, stream>>>(qb, kbuf, vt, out);
}

// Round 4
// 80.632 us; speedup vs baseline: 13.1383x; 2.1534x over previous
//
#include <hip/hip_runtime.h>
#include <hip/hip_bf16.h>

#define BATCH 8
#define SEQ   2048
#define CDIM  1024
#define HDIM  64
#define NROWS (BATCH*SEQ)   // 16384

typedef __attribute__((ext_vector_type(8))) short bf16x8;
typedef __attribute__((ext_vector_type(4))) float f32x4;

// 0.125 (1/sqrt(64)) * log2(e) — folded into Wq so QK^T emerges in exp2 units
#define QSCALE 0.18033688011112042f

__device__ inline ushort f2bf(float f) {
    union { float f; uint u; } x; x.f = f;
    uint r = (x.u + 0x7fffu + ((x.u >> 16) & 1u)) >> 16;
    return (ushort)r;
}

// ---------------------------------------------------------------------------
// Kernel 0: pack W^T into bf16  wp[192][1024];  n<64: Wq*QSCALE, <128: Wk, else Wv
// ---------------------------------------------------------------------------
__global__ __launch_bounds__(256) void wpack_kernel(
    const float* __restrict__ Wq, const float* __restrict__ Wk,
    const float* __restrict__ Wv, ushort* __restrict__ wp)
{
    const int n = blockIdx.x;            // 0..191
    const int which = n >> 6, nl = n & 63;
    const float* W = (which == 0) ? Wq : (which == 1) ? Wk : Wv;
    const float sc = (which == 0) ? QSCALE : 1.0f;
    for (int c = threadIdx.x; c < CDIM; c += 256)
        wp[(size_t)n * CDIM + c] = f2bf(W[(size_t)c * HDIM + nl] * sc);
}

// ---------------------------------------------------------------------------
// Kernel 1: QKV GEMM, bf16 MFMA, 2-phase reg-staged pipeline.
// 256 blocks x 512 threads (8 waves = 4 row-groups x 2 col-groups).
// Wave owns 16 rows x 96 cols.  Next K-tile's global loads issue before the
// current tile's ds_read+MFMA; ds_write lands after the barrier.
// ---------------------------------------------------------------------------
__global__ __launch_bounds__(512) void qkv_gemm(
    const float* __restrict__ x, const ushort* __restrict__ wp,
    ushort* __restrict__ qb, ushort* __restrict__ kbuf, ushort* __restrict__ vt)
{
    __shared__ ushort xs[64 * 64];   // [row][c] bf16, XOR-swizzled, 8KB
    __shared__ ushort ws[192 * 64];  // [n][c]  bf16, XOR-swizzled, 24KB
    const int t = threadIdx.x;
    const int w = t >> 6, lane = t & 63;
    const int rowg = w & 3, colg = w >> 2;
    const int m0 = blockIdx.x * 64;

    f32x4 acc[6];
    #pragma unroll
    for (int i = 0; i < 6; ++i) acc[i] = (f32x4){0.f, 0.f, 0.f, 0.f};

    // staging decomposition (per thread): x = 2 x float4, w = 3 x uint4
    const int xrow0 = t >> 4,          xc40 = t & 15;
    const int xrow1 = (t + 512) >> 4,  xc41 = (t + 512) & 15;
    const int wn0 = t >> 3,            wc80 = t & 7;
    const int wn1 = (t + 512) >> 3,    wc81 = (t + 512) & 7;
    const int wn2 = (t + 1024) >> 3,   wc82 = (t + 1024) & 7;

    float4 xr0, xr1;
    uint4  wr0, wr1, wr2;

#define LOAD_TILES(KK)                                                          \
    xr0 = reinterpret_cast<const float4*>(x + (size_t)(m0 + xrow0) * CDIM + (KK))[xc40]; \
    xr1 = reinterpret_cast<const float4*>(x + (size_t)(m0 + xrow1) * CDIM + (KK))[xc41]; \
    wr0 = reinterpret_cast<const uint4*>(wp + (size_t)wn0 * CDIM + (KK))[wc80];          \
    wr1 = reinterpret_cast<const uint4*>(wp + (size_t)wn1 * CDIM + (KK))[wc81];          \
    wr2 = reinterpret_cast<const uint4*>(wp + (size_t)wn2 * CDIM + (KK))[wc82];

#define WRITE_TILES()                                                           \
    {                                                                           \
        ushort4 b0 = make_ushort4(f2bf(xr0.x), f2bf(xr0.y), f2bf(xr0.z), f2bf(xr0.w)); \
        ushort4 b1 = make_ushort4(f2bf(xr1.x), f2bf(xr1.y), f2bf(xr1.z), f2bf(xr1.w)); \
        int by0 = (xrow0 * 128 + xc40 * 8) ^ ((xrow0 & 7) << 4);                \
        int by1 = (xrow1 * 128 + xc41 * 8) ^ ((xrow1 & 7) << 4);                \
        *reinterpret_cast<ushort4*>(reinterpret_cast<char*>(xs) + by0) = b0;    \
        *reinterpret_cast<ushort4*>(reinterpret_cast<char*>(xs) + by1) = b1;    \
        int wy0 = (wn0 * 128 + wc80 * 16) ^ ((wn0 & 7) << 4);                   \
        int wy1 = (wn1 * 128 + wc81 * 16) ^ ((wn1 & 7) << 4);                   \
        int wy2 = (wn2 * 128 + wc82 * 16) ^ ((wn2 & 7) << 4);                   \
        *reinterpret_cast<uint4*>(reinterpret_cast<char*>(ws) + wy0) = wr0;     \
        *reinterpret_cast<uint4*>(reinterpret_cast<char*>(ws) + wy1) = wr1;     \
        *reinterpret_cast<uint4*>(reinterpret_cast<char*>(ws) + wy2) = wr2;     \
    }

    // prologue: stage tile 0
    LOAD_TILES(0);
    WRITE_TILES();
    __syncthreads();

    const int arow = rowg * 16 + (lane & 15);
    for (int step = 0; step < 16; ++step) {
        if (step < 15) { LOAD_TILES((step + 1) * 64); }   // in flight over MFMA
        #pragma unroll
        for (int c32 = 0; c32 < 2; ++c32) {
            const int abyte = (arow * 128 + (lane >> 4) * 16 + c32 * 64) ^ ((arow & 7) << 4);
            bf16x8 a = *reinterpret_cast<const bf16x8*>(reinterpret_cast<char*>(xs) + abyte);
            #pragma unroll
            for (int nf = 0; nf < 6; ++nf) {
                const int n = (colg * 6 + nf) * 16 + (lane & 15);
                const int bbyte = (n * 128 + (lane >> 4) * 16 + c32 * 64) ^ ((n & 7) << 4);
                bf16x8 b = *reinterpret_cast<const bf16x8*>(reinterpret_cast<char*>(ws) + bbyte);
                acc[nf] = __builtin_amdgcn_mfma_f32_16x16x32_bf16(a, b, acc[nf], 0, 0, 0);
            }
        }
        __syncthreads();                 // all waves done reading LDS
        if (step < 15) {
            WRITE_TILES();               // waits vmcnt via data dep
            __syncthreads();
        }
    }
#undef LOAD_TILES
#undef WRITE_TILES

    // epilogue: C layout col = lane&15 (n), row = (lane>>4)*4 + r
    #pragma unroll
    for (int nf = 0; nf < 6; ++nf) {
        const int n = (colg * 6 + nf) * 16 + (lane & 15);
        #pragma unroll
        for (int r = 0; r < 4; ++r) {
            const int grow = m0 + rowg * 16 + (lane >> 4) * 4 + r;
            const ushort bv = f2bf(acc[nf][r]);
            if (n < 64) {
                qb[(size_t)grow * 64 + n] = bv;
            } else if (n < 128) {
                kbuf[(size_t)grow * 64 + (n - 64)] = bv;
            } else {
                const int b = grow >> 11, tt = grow & 2047;
                vt[(((size_t)b * 64 + (n - 128)) << 11) + tt] = bv;
            }
        }
    }
}

// ---------------------------------------------------------------------------
// Kernel 2: MFMA flash attention, split-K across 4 waves per block.
// 1024 blocks x 256 threads; block = one 16-row q-tile; wave w takes key
// tiles kt ≡ w (mod 4) with private (m,l,O) and a per-wave P buffer (no
// barriers in the loop). One barrier, then block-level softmax merge.
// ---------------------------------------------------------------------------
__global__ __launch_bounds__(256) void attn_mfma(
    const ushort* __restrict__ qb, const ushort* __restrict__ kbuf,
    const ushort* __restrict__ vt, float* __restrict__ out)
{
    __shared__ ushort P[4][1024];        // per-wave P round-trip, 8KB
    __shared__ float Osm[4][16][64];     // per-wave partial O, 16KB
    __shared__ float msm[4][16];
    __shared__ float lsm[4][16];

    const int w    = threadIdx.x >> 6;
    const int lane = threadIdx.x & 63;
    const int g = blockIdx.x;
    const int pid = g >> 1, s = g & 1;
    const int qt = s ? (127 - (pid & 127)) : (pid & 127);
    const int batch = ((pid >> 7) << 1) | s;
    const int qbase = qt * 16;
    const int row0 = batch * SEQ + qbase;

    // Q A-fragments (prescaled by QSCALE at GEMM time)
    const int c0 = (lane >> 4) * 8;
    const ushort* qp = qb + (size_t)(row0 + (lane & 15)) * 64 + c0;
    bf16x8 aq0 = *reinterpret_cast<const bf16x8*>(qp);
    bf16x8 aq1 = *reinterpret_cast<const bf16x8*>(qp + 32);

    f32x4 O[4];
    #pragma unroll
    for (int i = 0; i < 4; ++i) O[i] = (f32x4){0.f, 0.f, 0.f, 0.f};
    float m[4]    = {-1e30f, -1e30f, -1e30f, -1e30f};
    float lsum[4] = {0.f, 0.f, 0.f, 0.f};

    const ushort* kB = kbuf + (size_t)batch * SEQ * 64;
    const ushort* vB = vt + (size_t)batch * 64 * SEQ;
    char* pw = reinterpret_cast<char*>(P[w]);

    const int ntiles = (qbase >> 6) + 1;
    for (int kt = w; kt < ntiles; kt += 4) {
        const int j0 = kt * 64;
        // ---- QK^T: S[16 q][64 k] in exp2 units ----
        f32x4 S[4];
        #pragma unroll
        for (int kb = 0; kb < 4; ++kb) {
            const int key = j0 + kb * 16 + (lane & 15);
            const ushort* kp = kB + (size_t)key * 64 + c0;
            bf16x8 b0 = *reinterpret_cast<const bf16x8*>(kp);
            bf16x8 b1 = *reinterpret_cast<const bf16x8*>(kp + 32);
            f32x4 z = (f32x4){0.f, 0.f, 0.f, 0.f};
            z = __builtin_amdgcn_mfma_f32_16x16x32_bf16(aq0, b0, z, 0, 0, 0);
            z = __builtin_amdgcn_mfma_f32_16x16x32_bf16(aq1, b1, z, 0, 0, 0);
            S[kb] = z;
        }
        // ---- V prefetch (independent of S; overlaps softmax VALU chain) ----
        bf16x8 v0[4], v1[4];
        #pragma unroll
        for (int dt = 0; dt < 4; ++dt) {
            const int d = dt * 16 + (lane & 15);
            const ushort* vp = vB + (size_t)d * SEQ + j0 + (lane >> 4) * 8;
            v0[dt] = *reinterpret_cast<const bf16x8*>(vp);
            v1[dt] = *reinterpret_cast<const bf16x8*>(vp + 32);
        }
        // ---- causal mask ----
        #pragma unroll
        for (int kb = 0; kb < 4; ++kb) {
            const int key = j0 + kb * 16 + (lane & 15);
            #pragma unroll
            for (int r = 0; r < 4; ++r) {
                const int qr = qbase + (lane >> 4) * 4 + r;
                if (key > qr) S[kb][r] = -1e30f;
            }
        }
        // ---- online softmax (row lives in 16 lanes of a quarter) ----
        float corr[4];
        #pragma unroll
        for (int r = 0; r < 4; ++r) {
            float tmax = fmaxf(fmaxf(S[0][r], S[1][r]), fmaxf(S[2][r], S[3][r]));
            #pragma unroll
            for (int off = 1; off <= 8; off <<= 1)
                tmax = fmaxf(tmax, __shfl_xor(tmax, off, 64));
            const float mnew = fmaxf(m[r], tmax);
            corr[r] = exp2f(m[r] - mnew);
            m[r] = mnew;
        }
        float psum[4] = {0.f, 0.f, 0.f, 0.f};
        #pragma unroll
        for (int kb = 0; kb < 4; ++kb) {
            #pragma unroll
            for (int r = 0; r < 4; ++r) {
                const float pv = exp2f(S[kb][r] - m[r]);   // masked -> 0
                S[kb][r] = pv;
                psum[r] += pv;
            }
        }
        #pragma unroll
        for (int r = 0; r < 4; ++r) {
            float ps = psum[r];
            #pragma unroll
            for (int off = 1; off <= 8; off <<= 1)
                ps += __shfl_xor(ps, off, 64);
            lsum[r] = lsum[r] * corr[r] + ps;
        }
        #pragma unroll
        for (int dt = 0; dt < 4; ++dt)
            #pragma unroll
            for (int r = 0; r < 4; ++r)
                O[dt][r] *= corr[r];
        // ---- P: C-layout -> per-wave LDS (swizzled) -> A-layout ----
        // intra-wave only: LDS pipe is in-order per wave; compiler fence
        // pins program order, no s_barrier needed.
        #pragma unroll
        for (int kb = 0; kb < 4; ++kb) {
            #pragma unroll
            for (int r = 0; r < 4; ++r) {
                const int prow = (lane >> 4) * 4 + r;
                const int pcol = kb * 16 + (lane & 15);
                const int byte = (prow * 128 + pcol * 2) ^ ((prow & 7) << 4);
                *reinterpret_cast<ushort*>(pw + byte) = f2bf(S[kb][r]);
            }
        }
        asm volatile("" ::: "memory");   // compile-time ordering fence
        const int prow2 = lane & 15;
        const int pb0 = (prow2 * 128 + (lane >> 4) * 16) ^ ((prow2 & 7) << 4);
        const int pb1 = (prow2 * 128 + (lane >> 4) * 16 + 64) ^ ((prow2 & 7) << 4);
        bf16x8 pa0 = *reinterpret_cast<const bf16x8*>(pw + pb0);
        bf16x8 pa1 = *reinterpret_cast<const bf16x8*>(pw + pb1);
        // ---- PV: O += P[16][64] * V[64][64] ----
        #pragma unroll
        for (int dt = 0; dt < 4; ++dt) {
            O[dt] = __builtin_amdgcn_mfma_f32_16x16x32_bf16(pa0, v0[dt], O[dt], 0, 0, 0);
            O[dt] = __builtin_amdgcn_mfma_f32_16x16x32_bf16(pa1, v1[dt], O[dt], 0, 0, 0);
        }
    }

    // ---- publish per-wave partials ----
    #pragma unroll
    for (int dt = 0; dt < 4; ++dt)
        #pragma unroll
        for (int r = 0; r < 4; ++r)
            Osm[w][(lane >> 4) * 4 + r][dt * 16 + (lane & 15)] = O[dt][r];
    if ((lane & 15) == 0) {
        #pragma unroll
        for (int r = 0; r < 4; ++r) {
            msm[w][(lane >> 4) * 4 + r] = m[r];
            lsm[w][(lane >> 4) * 4 + r] = lsum[r];
        }
    }
    __syncthreads();

    // ---- merge 4 partial (m,l,O) and write out ----
    for (int e = threadIdx.x; e < 1024; e += 256) {
        const int row = e >> 6, col = e & 63;
        const float mx = fmaxf(fmaxf(msm[0][row], msm[1][row]),
                               fmaxf(msm[2][row], msm[3][row]));
        float accv = 0.f, lv = 0.f;
        #pragma unroll
        for (int ww = 0; ww < 4; ++ww) {
            const float sc = exp2f(msm[ww][row] - mx);
            accv += Osm[ww][row][col] * sc;
            lv   += lsm[ww][row] * sc;
        }
        out[(size_t)(row0 + row) * 64 + col] = accv / lv;
    }
}

extern "C" void kernel_launch(void* const* d_in, const int* in_sizes, int n_in,
                              void* d_out, int out_size, void* d_ws, size_t ws_size,
                              hipStream_t stream) {
    const float* x  = (const float*)d_in[0];
    const float* Wq = (const float*)d_in[1];
    const float* Wk = (const float*)d_in[2];
    const float* Wv = (const float*)d_in[3];
    float* out = (float*)d_out;

    ushort* qb   = (ushort*)d_ws;                    // 2MB
    ushort* kbuf = qb + (size_t)NROWS * 64;          // 2MB
    ushort* vt   = kbuf + (size_t)NROWS * 64;        // 2MB (transposed V)
    ushort* wp   = vt + (size_t)NROWS * 64;          // 384KB packed W^T

    wpack_kernel<<<192, 256, 0, stream>>>(Wq, Wk, Wv, wp);
    qkv_gemm<<<NROWS / 64, 512, 0, stream>>>(x, wp, qb, kbuf, vt);
    attn_mfma<<<1024, 256, 0, stream>>>(qb, kbuf, vt, out);
}

// Round 5
// 66.658 us; speedup vs baseline: 15.8927x; 1.2096x over previous
//
#include <hip/hip_runtime.h>
#include <hip/hip_bf16.h>

#define BATCH 8
#define SEQ   2048
#define CDIM  1024
#define HDIM  64
#define NROWS (BATCH*SEQ)   // 16384

typedef __attribute__((ext_vector_type(8))) short bf16x8;
typedef __attribute__((ext_vector_type(4))) float f32x4;

// 0.125 (1/sqrt(64)) * log2(e) — folded into Wq so QK^T emerges in exp2 units
#define QSCALE 0.18033688011112042f

__device__ inline ushort f2bf(float f) {
    union { float f; uint u; } x; x.f = f;
    uint r = (x.u + 0x7fffu + ((x.u >> 16) & 1u)) >> 16;
    return (ushort)r;
}

// ---------------------------------------------------------------------------
// Kernel 0: pack W^T into bf16  wp[192][1024];  n<64: Wq*QSCALE, <128: Wk, else Wv
// ---------------------------------------------------------------------------
__global__ __launch_bounds__(256) void wpack_kernel(
    const float* __restrict__ Wq, const float* __restrict__ Wk,
    const float* __restrict__ Wv, ushort* __restrict__ wp)
{
    const int n = blockIdx.x;            // 0..191
    const int which = n >> 6, nl = n & 63;
    const float* W = (which == 0) ? Wq : (which == 1) ? Wk : Wv;
    const float sc = (which == 0) ? QSCALE : 1.0f;
    for (int c = threadIdx.x; c < CDIM; c += 256)
        wp[(size_t)n * CDIM + c] = f2bf(W[(size_t)c * HDIM + nl] * sc);
}

// ---------------------------------------------------------------------------
// Kernel 1: QKV GEMM, bf16 MFMA, 2-deep reg pipeline + double-buffered LDS.
// 256 blocks x 512 threads (8 waves = 4 row-groups x 2 col-groups).
// Loads for tile t+2 issue one full step before their ds_write -> vmcnt wait
// covered by an entire MFMA phase.  One barrier per tile.
// ---------------------------------------------------------------------------
__global__ __launch_bounds__(512) void qkv_gemm(
    const float* __restrict__ x, const ushort* __restrict__ wp,
    ushort* __restrict__ qb, ushort* __restrict__ kbuf, ushort* __restrict__ vt)
{
    __shared__ ushort xs[2][64 * 64];    // 16KB  [row][c] bf16, XOR-swizzled
    __shared__ ushort ws[2][192 * 64];   // 48KB  [n][c]  bf16, XOR-swizzled
    const int t = threadIdx.x;
    const int w = t >> 6, lane = t & 63;
    const int rowg = w & 3, colg = w >> 2;
    const int m0 = blockIdx.x * 64;

    f32x4 acc[6];
    #pragma unroll
    for (int i = 0; i < 6; ++i) acc[i] = (f32x4){0.f, 0.f, 0.f, 0.f};

    const int xrow0 = t >> 4,          xc40 = t & 15;
    const int xrow1 = (t + 512) >> 4,  xc41 = (t + 512) & 15;
    const int wn0 = t >> 3,            wc80 = t & 7;
    const int wn1 = (t + 512) >> 3,    wc81 = (t + 512) & 7;
    const int wn2 = (t + 1024) >> 3,   wc82 = (t + 1024) & 7;

    float4 xr0a, xr1a; uint4 wr0a, wr1a, wr2a;
    float4 xr0b, xr1b; uint4 wr0b, wr1b, wr2b;

#define LOADS(S, KK)                                                                     \
    xr0##S = reinterpret_cast<const float4*>(x + (size_t)(m0 + xrow0) * CDIM + (KK))[xc40]; \
    xr1##S = reinterpret_cast<const float4*>(x + (size_t)(m0 + xrow1) * CDIM + (KK))[xc41]; \
    wr0##S = reinterpret_cast<const uint4*>(wp + (size_t)wn0 * CDIM + (KK))[wc80];          \
    wr1##S = reinterpret_cast<const uint4*>(wp + (size_t)wn1 * CDIM + (KK))[wc81];          \
    wr2##S = reinterpret_cast<const uint4*>(wp + (size_t)wn2 * CDIM + (KK))[wc82];

#define WRITES(S, BUF)                                                                   \
    {                                                                                    \
        ushort4 b0 = make_ushort4(f2bf(xr0##S.x), f2bf(xr0##S.y), f2bf(xr0##S.z), f2bf(xr0##S.w)); \
        ushort4 b1 = make_ushort4(f2bf(xr1##S.x), f2bf(xr1##S.y), f2bf(xr1##S.z), f2bf(xr1##S.w)); \
        int by0 = (xrow0 * 128 + xc40 * 8) ^ ((xrow0 & 7) << 4);                         \
        int by1 = (xrow1 * 128 + xc41 * 8) ^ ((xrow1 & 7) << 4);                         \
        *reinterpret_cast<ushort4*>(reinterpret_cast<char*>(xs[BUF]) + by0) = b0;        \
        *reinterpret_cast<ushort4*>(reinterpret_cast<char*>(xs[BUF]) + by1) = b1;        \
        int wy0 = (wn0 * 128 + wc80 * 16) ^ ((wn0 & 7) << 4);                            \
        int wy1 = (wn1 * 128 + wc81 * 16) ^ ((wn1 & 7) << 4);                            \
        int wy2 = (wn2 * 128 + wc82 * 16) ^ ((wn2 & 7) << 4);                            \
        *reinterpret_cast<uint4*>(reinterpret_cast<char*>(ws[BUF]) + wy0) = wr0##S;      \
        *reinterpret_cast<uint4*>(reinterpret_cast<char*>(ws[BUF]) + wy1) = wr1##S;      \
        *reinterpret_cast<uint4*>(reinterpret_cast<char*>(ws[BUF]) + wy2) = wr2##S;      \
    }

#define MFMA_STEP(BUF)                                                                   \
    {                                                                                    \
        _Pragma("unroll")                                                                \
        for (int c32 = 0; c32 < 2; ++c32) {                                              \
            const int abyte = (arow * 128 + (lane >> 4) * 16 + c32 * 64) ^ ((arow & 7) << 4); \
            bf16x8 a = *reinterpret_cast<const bf16x8*>(reinterpret_cast<char*>(xs[BUF]) + abyte); \
            _Pragma("unroll")                                                            \
            for (int nf = 0; nf < 6; ++nf) {                                             \
                const int n = (colg * 6 + nf) * 16 + (lane & 15);                        \
                const int bbyte = (n * 128 + (lane >> 4) * 16 + c32 * 64) ^ ((n & 7) << 4); \
                bf16x8 b = *reinterpret_cast<const bf16x8*>(reinterpret_cast<char*>(ws[BUF]) + bbyte); \
                acc[nf] = __builtin_amdgcn_mfma_f32_16x16x32_bf16(a, b, acc[nf], 0, 0, 0); \
            }                                                                            \
        }                                                                                \
    }

    const int arow = rowg * 16 + (lane & 15);

    LOADS(a, 0)
    LOADS(b, 64)
    WRITES(a, 0)
    __syncthreads();

    for (int step = 0; step < 16; step += 2) {
        if (step + 2 < 16) { LOADS(a, (step + 2) * 64) }
        MFMA_STEP(0)
        WRITES(b, 1)
        __syncthreads();
        if (step + 3 < 16) { LOADS(b, (step + 3) * 64) }
        MFMA_STEP(1)
        if (step + 2 < 16) { WRITES(a, 0) }
        __syncthreads();
    }
#undef LOADS
#undef WRITES
#undef MFMA_STEP

    // epilogue: C layout col = lane&15 (n), row = (lane>>4)*4 + r
    #pragma unroll
    for (int nf = 0; nf < 6; ++nf) {
        const int n = (colg * 6 + nf) * 16 + (lane & 15);
        #pragma unroll
        for (int r = 0; r < 4; ++r) {
            const int grow = m0 + rowg * 16 + (lane >> 4) * 4 + r;
            const ushort bv = f2bf(acc[nf][r]);
            if (n < 64) {
                qb[(size_t)grow * 64 + n] = bv;
            } else if (n < 128) {
                kbuf[(size_t)grow * 64 + (n - 64)] = bv;
            } else {
                const int b = grow >> 11, tt = grow & 2047;
                vt[(((size_t)b * 64 + (n - 128)) << 11) + tt] = bv;
            }
        }
    }
}

// ---------------------------------------------------------------------------
// Kernel 2: MFMA flash attention, balanced pair scheduling.
// 512 blocks x 512 threads (8 waves).  Block owns q-tiles (qtA=pairIdx,
// qtB=127-pairIdx): ntA+ntB == 33 always.  Wave w processes combined tile
// indices ≡ w (mod 8) — A-tiles first, then B-tiles, sequentially with ONE
// live state; A-partials dumped to LDS at the (wave-uniform) transition.
// 8-way softmax merge per q-tile after a single barrier.  XCD-swizzled
// blockIdx: each XCD owns one batch (K/V 512KB -> its private L2).
// ---------------------------------------------------------------------------
__global__ __launch_bounds__(512, 4) void attn_mfma(
    const ushort* __restrict__ qb, const ushort* __restrict__ kbuf,
    const ushort* __restrict__ vt, float* __restrict__ out)
{
    __shared__ float OsmA[8][16][64];    // 32KB  A partials
    __shared__ float regB[8][1024];      // 32KB  per-wave: P buffer (first 2KB) during loop, OsmB after
    __shared__ float msA[8][16], lsA[8][16], msB[8][16], lsB[8][16];

    const int w    = threadIdx.x >> 6;
    const int lane = threadIdx.x & 63;
    const int bid  = blockIdx.x;
    const int pid  = (bid & 7) * 64 + (bid >> 3);   // XCD swizzle: XCD x -> batch x
    const int batch = pid >> 6;
    const int pairIdx = pid & 63;
    const int qtA = pairIdx, qtB = 127 - pairIdx;
    const int ntA = (qtA >> 2) + 1;                 // ntA + ntB == 33

    const ushort* kB = kbuf + (size_t)batch * SEQ * 64;
    const ushort* vB = vt + (size_t)batch * 64 * SEQ;
    char* pw = reinterpret_cast<char*>(&regB[w][0]);

    const int c0 = (lane >> 4) * 8;
    int qbase = qtA * 16;
    bf16x8 aq0, aq1;
    {
        const ushort* qp = qb + (size_t)(batch * SEQ + qbase + (lane & 15)) * 64 + c0;
        aq0 = *reinterpret_cast<const bf16x8*>(qp);
        aq1 = *reinterpret_cast<const bf16x8*>(qp + 32);
    }

    f32x4 O[4];
    #pragma unroll
    for (int i = 0; i < 4; ++i) O[i] = (f32x4){0.f, 0.f, 0.f, 0.f};
    float m[4]    = {-1e30f, -1e30f, -1e30f, -1e30f};
    float lsum[4] = {0.f, 0.f, 0.f, 0.f};

#define DUMP_A()                                                              \
    {                                                                         \
        _Pragma("unroll")                                                     \
        for (int dt = 0; dt < 4; ++dt)                                        \
            _Pragma("unroll")                                                 \
            for (int r = 0; r < 4; ++r)                                       \
                OsmA[w][(lane >> 4) * 4 + r][dt * 16 + (lane & 15)] = O[dt][r]; \
        if ((lane & 15) == 0) {                                               \
            _Pragma("unroll")                                                 \
            for (int r = 0; r < 4; ++r) {                                     \
                msA[w][(lane >> 4) * 4 + r] = m[r];                           \
                lsA[w][(lane >> 4) * 4 + r] = lsum[r];                        \
            }                                                                 \
        }                                                                     \
    }

#define RESET_STATE()                                                         \
    {                                                                         \
        _Pragma("unroll")                                                     \
        for (int i = 0; i < 4; ++i) {                                         \
            O[i] = (f32x4){0.f, 0.f, 0.f, 0.f};                               \
            m[i] = -1e30f; lsum[i] = 0.f;                                     \
        }                                                                     \
    }

    int curB = 0;
    for (int c = w; c < 33; c += 8) {
        const int isB = (c >= ntA);
        if (isB && !curB) {            // wave-uniform transition A -> B
            DUMP_A()
            RESET_STATE()
            qbase = qtB * 16;
            const ushort* qp = qb + (size_t)(batch * SEQ + qbase + (lane & 15)) * 64 + c0;
            aq0 = *reinterpret_cast<const bf16x8*>(qp);
            aq1 = *reinterpret_cast<const bf16x8*>(qp + 32);
            curB = 1;
        }
        const int kt = isB ? (c - ntA) : c;
        const int j0 = kt * 64;

        // ---- QK^T: S[16 q][64 k] in exp2 units ----
        f32x4 S[4];
        #pragma unroll
        for (int kb = 0; kb < 4; ++kb) {
            const int key = j0 + kb * 16 + (lane & 15);
            const ushort* kp = kB + (size_t)key * 64 + c0;
            bf16x8 b0 = *reinterpret_cast<const bf16x8*>(kp);
            bf16x8 b1 = *reinterpret_cast<const bf16x8*>(kp + 32);
            f32x4 z = (f32x4){0.f, 0.f, 0.f, 0.f};
            z = __builtin_amdgcn_mfma_f32_16x16x32_bf16(aq0, b0, z, 0, 0, 0);
            z = __builtin_amdgcn_mfma_f32_16x16x32_bf16(aq1, b1, z, 0, 0, 0);
            S[kb] = z;
        }
        // ---- V prefetch (independent; overlaps softmax VALU chain) ----
        bf16x8 v0[4], v1[4];
        #pragma unroll
        for (int dt = 0; dt < 4; ++dt) {
            const int d = dt * 16 + (lane & 15);
            const ushort* vp = vB + (size_t)d * SEQ + j0 + (lane >> 4) * 8;
            v0[dt] = *reinterpret_cast<const bf16x8*>(vp);
            v1[dt] = *reinterpret_cast<const bf16x8*>(vp + 32);
        }
        // ---- causal mask ----
        #pragma unroll
        for (int kb = 0; kb < 4; ++kb) {
            const int key = j0 + kb * 16 + (lane & 15);
            #pragma unroll
            for (int r = 0; r < 4; ++r) {
                const int qr = qbase + (lane >> 4) * 4 + r;
                if (key > qr) S[kb][r] = -1e30f;
            }
        }
        // ---- online softmax (row lives in 16 lanes of a quarter) ----
        float corr[4];
        #pragma unroll
        for (int r = 0; r < 4; ++r) {
            float tmax = fmaxf(fmaxf(S[0][r], S[1][r]), fmaxf(S[2][r], S[3][r]));
            #pragma unroll
            for (int off = 1; off <= 8; off <<= 1)
                tmax = fmaxf(tmax, __shfl_xor(tmax, off, 64));
            const float mnew = fmaxf(m[r], tmax);
            corr[r] = exp2f(m[r] - mnew);
            m[r] = mnew;
        }
        float psum[4] = {0.f, 0.f, 0.f, 0.f};
        #pragma unroll
        for (int kb = 0; kb < 4; ++kb) {
            #pragma unroll
            for (int r = 0; r < 4; ++r) {
                const float pv = exp2f(S[kb][r] - m[r]);   // masked -> 0
                S[kb][r] = pv;
                psum[r] += pv;
            }
        }
        #pragma unroll
        for (int r = 0; r < 4; ++r) {
            float ps = psum[r];
            #pragma unroll
            for (int off = 1; off <= 8; off <<= 1)
                ps += __shfl_xor(ps, off, 64);
            lsum[r] = lsum[r] * corr[r] + ps;
        }
        #pragma unroll
        for (int dt = 0; dt < 4; ++dt)
            #pragma unroll
            for (int r = 0; r < 4; ++r)
                O[dt][r] *= corr[r];
        // ---- P: C-layout -> per-wave LDS (swizzled) -> A-layout ----
        #pragma unroll
        for (int kb = 0; kb < 4; ++kb) {
            #pragma unroll
            for (int r = 0; r < 4; ++r) {
                const int prow = (lane >> 4) * 4 + r;
                const int pcol = kb * 16 + (lane & 15);
                const int byte = (prow * 128 + pcol * 2) ^ ((prow & 7) << 4);
                *reinterpret_cast<ushort*>(pw + byte) = f2bf(S[kb][r]);
            }
        }
        asm volatile("" ::: "memory");   // compile-time ordering fence (intra-wave LDS is in-order)
        const int prow2 = lane & 15;
        const int pb0 = (prow2 * 128 + (lane >> 4) * 16) ^ ((prow2 & 7) << 4);
        const int pb1 = (prow2 * 128 + (lane >> 4) * 16 + 64) ^ ((prow2 & 7) << 4);
        bf16x8 pa0 = *reinterpret_cast<const bf16x8*>(pw + pb0);
        bf16x8 pa1 = *reinterpret_cast<const bf16x8*>(pw + pb1);
        // ---- PV: O += P[16][64] * V[64][64] ----
        #pragma unroll
        for (int dt = 0; dt < 4; ++dt) {
            O[dt] = __builtin_amdgcn_mfma_f32_16x16x32_bf16(pa0, v0[dt], O[dt], 0, 0, 0);
            O[dt] = __builtin_amdgcn_mfma_f32_16x16x32_bf16(pa1, v1[dt], O[dt], 0, 0, 0);
        }
    }

    if (!curB) {            // safety: wave had no B tiles (shouldn't happen)
        DUMP_A()
        RESET_STATE()
        curB = 1;
    }
#undef DUMP_A
#undef RESET_STATE

    // dump B partials into regB[w] (P region no longer needed)
    #pragma unroll
    for (int dt = 0; dt < 4; ++dt)
        #pragma unroll
        for (int r = 0; r < 4; ++r)
            regB[w][((lane >> 4) * 4 + r) * 64 + dt * 16 + (lane & 15)] = O[dt][r];
    if ((lane & 15) == 0) {
        #pragma unroll
        for (int r = 0; r < 4; ++r) {
            msB[w][(lane >> 4) * 4 + r] = m[r];
            lsB[w][(lane >> 4) * 4 + r] = lsum[r];
        }
    }
    __syncthreads();

    // ---- merge 8 partials for q-tile A ----
    for (int ee = threadIdx.x; ee < 1024; ee += 512) {
        const int row = ee >> 6, col = ee & 63;
        float mx = -1e30f;
        #pragma unroll
        for (int ww = 0; ww < 8; ++ww) mx = fmaxf(mx, msA[ww][row]);
        float accv = 0.f, lv = 0.f;
        #pragma unroll
        for (int ww = 0; ww < 8; ++ww) {
            const float sc = exp2f(msA[ww][row] - mx);
            accv += OsmA[ww][row][col] * sc;
            lv   += lsA[ww][row] * sc;
        }
        out[(size_t)(batch * SEQ + qtA * 16 + row) * 64 + col] = accv / lv;
    }
    // ---- merge 8 partials for q-tile B ----
    for (int ee = threadIdx.x; ee < 1024; ee += 512) {
        const int row = ee >> 6, col = ee & 63;
        float mx = -1e30f;
        #pragma unroll
        for (int ww = 0; ww < 8; ++ww) mx = fmaxf(mx, msB[ww][row]);
        float accv = 0.f, lv = 0.f;
        #pragma unroll
        for (int ww = 0; ww < 8; ++ww) {
            const float sc = exp2f(msB[ww][row] - mx);
            accv += regB[ww][row * 64 + col] * sc;
            lv   += lsB[ww][row] * sc;
        }
        out[(size_t)(batch * SEQ + qtB * 16 + row) * 64 + col] = accv / lv;
    }
}

extern "C" void kernel_launch(void* const* d_in, const int* in_sizes, int n_in,
                              void* d_out, int out_size, void* d_ws, size_t ws_size,
                              hipStream_t stream) {
    const float* x  = (const float*)d_in[0];
    const float* Wq = (const float*)d_in[1];
    const float* Wk = (const float*)d_in[2];
    const float* Wv = (const float*)d_in[3];
    float* out = (float*)d_out;

    ushort* qb   = (ushort*)d_ws;                    // 2MB
    ushort* kbuf = qb + (size_t)NROWS * 64;          // 2MB
    ushort* vt   = kbuf + (size_t)NROWS * 64;        // 2MB (transposed V)
    ushort* wp   = vt + (size_t)NROWS * 64;          // 384KB packed W^T

    wpack_kernel<<<192, 256, 0, stream>>>(Wq, Wk, Wv, wp);
    qkv_gemm<<<NROWS / 64, 512, 0, stream>>>(x, wp, qb, kbuf, vt);
    attn_mfma<<<512, 512, 0, stream>>>(qb, kbuf, vt, out);
}